// Round 7
// baseline (1788.210 us; speedup 1.0000x reference)
//
#include <hip/hip_runtime.h>
#include <hip/hip_bf16.h>
#include <math.h>

// ---------------------------------------------------------------------------
// CART soft-decision-tree fused pipeline — round 7.
// r6 post-mortem: __launch_bounds__(256,3) (168-reg cap) spilled the 64-reg
// MFMA accumulator to scratch -> 5.07 GB/dispatch HBM traffic, 1657 us.
// Fix: launch_bounds(256,2) (256-reg budget) + scalarized staging temps.
//   out[b,o] = (1/T) sum_t relu(sigmoid(xn@P_t - cut_t) @ W1_t + b1_t) @ W2_t * tw_t + bias
// GEMM1: x (fp32 split to bf16 hi/lo in-kernel) @ A (bf16 hi/lo, pre-split,
//        pre-transposed by k_sparsemax) via mfma_f32_16x16x32_bf16,
//        3 products (hh + lh + hl). MLP stays fp32 VALU.
// ---------------------------------------------------------------------------

#define B_ROWS 65536
#define F_DIM  256
#define T_TREES 32
#define NC     1024
#define BN_EPS 1e-5f

// ws layout (float offsets)
#define WS_SUM    0
#define WS_SUMSQ  256
#define WS_SCALE  512
#define WS_SHIFT  768
#define WS_BIAS   1024        // 16
#define WS_C2     1040        // 1024
#define WS_AHT    2560        // A^T hi: [1024 cols][256 f] bf16 = 131072 floats
#define WS_ALT    133632      // A^T lo: same size
#define WS_PART   264704      // 8 * 65536*16
#define WS_FLOATS_ATOMIC  264704
#define WS_FLOATS_PARTIAL (264704 + 8*1048576)

typedef __attribute__((ext_vector_type(8))) short bf16x8;   // 4 VGPRs (A/B frag)
typedef __attribute__((ext_vector_type(4))) float f32x4;    // C/D frag

// Truncate-split: v = hi + lo, lo exact residual.
__device__ __forceinline__ void split_bf16(float v, unsigned short& h, unsigned short& l) {
    unsigned u = __builtin_bit_cast(unsigned, v);
    h = (unsigned short)(u >> 16);
    float hf = __builtin_bit_cast(float, (unsigned)h << 16);
    float lo = v - hf;
    l = (unsigned short)(__builtin_bit_cast(unsigned, lo) >> 16);
}

__device__ __forceinline__ void split4(float4 v, bf16x8& hacc, bf16x8& lacc, int off) {
    unsigned short h, l;
    split_bf16(v.x, h, l); hacc[off + 0] = (short)h; lacc[off + 0] = (short)l;
    split_bf16(v.y, h, l); hacc[off + 1] = (short)h; lacc[off + 1] = (short)l;
    split_bf16(v.z, h, l); hacc[off + 2] = (short)h; lacc[off + 2] = (short)l;
    split_bf16(v.w, h, l); hacc[off + 3] = (short)h; lacc[off + 3] = (short)l;
}

__global__ void k_zero(float* ws) {
    ws[threadIdx.x] = 0.0f;
}

__global__ void k_stats(const float* __restrict__ x, float* __restrict__ ws) {
    const int f  = threadIdx.x;
    const int r0 = blockIdx.x * 128;
    float s = 0.f, sq = 0.f;
    const float* p = x + (size_t)r0 * F_DIM + f;
#pragma unroll 4
    for (int r = 0; r < 128; ++r) { float v = p[(size_t)r * F_DIM]; s += v; sq += v * v; }
    atomicAdd(&ws[WS_SUM  + f], s);
    atomicAdd(&ws[WS_SUMSQ + f], sq);
}

__global__ void k_finalize(const float* __restrict__ gamma, const float* __restrict__ beta,
                           const float* __restrict__ b2, const float* __restrict__ tw,
                           float* __restrict__ ws) {
    const int f = threadIdx.x;
    const float inv = 1.0f / (float)B_ROWS;
    float mean = ws[WS_SUM + f] * inv;
    float var  = ws[WS_SUMSQ + f] * inv - mean * mean;
    float sc   = gamma[f] / sqrtf(var + BN_EPS);
    ws[WS_SCALE + f] = sc;
    ws[WS_SHIFT + f] = beta[f] - mean * sc;
    if (f < 16) {
        float acc = 0.f;
        for (int t = 0; t < T_TREES; ++t) acc += b2[t * 16 + f] * tw[t * 16 + f];
        ws[WS_BIAS + f] = acc * (1.0f / (float)T_TREES);
    }
}

__global__ void k_sparsemax(const float* __restrict__ fsm, const float* __restrict__ cut,
                            float* __restrict__ ws) {
    __shared__ float zs[256];
    __shared__ float zo[256];
    __shared__ float csA[256];
    __shared__ float csB[256];
    __shared__ float red[256];
    __shared__ int   redi[256];
    const int tid = threadIdx.x;
    const int col = blockIdx.x;           // t*32 + s
    const int t = col >> 5, s = col & 31;
    const float z = fsm[t * 8192 + tid * 32 + s];
    zo[tid] = z;
    zs[tid] = z;
    for (int size = 2; size <= 256; size <<= 1) {
        for (int stride = size >> 1; stride > 0; stride >>= 1) {
            __syncthreads();
            const int p = tid ^ stride;
            const float a = zs[tid], b = zs[p];
            __syncthreads();
            const bool up    = ((tid & size) == 0);
            const bool lower = ((tid & stride) == 0);
            zs[tid] = (lower == up) ? fminf(a, b) : fmaxf(a, b);
        }
    }
    __syncthreads();
    csA[tid] = zs[255 - tid];
    __syncthreads();
    float* src = csA; float* dst = csB;
    for (int off = 1; off < 256; off <<= 1) {
        float v = src[tid];
        if (tid >= off) v += src[tid - off];
        dst[tid] = v;
        __syncthreads();
        float* tmp = src; src = dst; dst = tmp;
    }
    const float zd = zs[255 - tid];
    const float kk = (float)(tid + 1);
    redi[tid] = (1.0f + kk * zd > src[tid]) ? 1 : 0;
    __syncthreads();
    for (int off = 128; off > 0; off >>= 1) {
        if (tid < off) redi[tid] += redi[tid + off];
        __syncthreads();
    }
    const int ksup = redi[0];
    const float tau = (src[ksup - 1] - 1.0f) / (float)ksup;
    const float P = fmaxf(zo[tid] - tau, 0.0f);
    const float av = ws[WS_SCALE + tid] * P;
    unsigned short h, l;
    split_bf16(av, h, l);
    ((unsigned short*)(ws + WS_AHT))[(size_t)col * 256 + tid] = h;
    ((unsigned short*)(ws + WS_ALT))[(size_t)col * 256 + tid] = l;
    red[tid] = ws[WS_SHIFT + tid] * P;
    __syncthreads();
    for (int off = 128; off > 0; off >>= 1) {
        if (tid < off) red[tid] += red[tid + off];
        __syncthreads();
    }
    if (tid == 0) ws[WS_C2 + col] = red[0] - cut[col];
}

// ---------------------------------------------------------------------------
// k_main: 128x128 tile, 256 thr = 4 waves (2x2 of 64x64). grid (512, 8).
// LDS (40960 B): K-phase shorts XH@0 XL@5120 BH@10240 BL@15360, rows [*][40];
// MLP-phase floats scT@0 [32][132], hT@4224 [32][132], W1T@8448 [32][36],
//   W2T@9600 [16][36], b1@10176 [32].
// launch_bounds(256,2): 256-reg budget so the 64-reg acc stays in registers
// (r6: 168-reg cap spilled it -> 5 GB scratch traffic).
// ---------------------------------------------------------------------------
template <int ATOMIC>
__global__ __launch_bounds__(256, 2) void k_main(
        const float* __restrict__ x, const float* __restrict__ W1g,
        const float* __restrict__ b1g, const float* __restrict__ W2g,
        const float* __restrict__ twg, float* __restrict__ ws,
        float* __restrict__ out) {
    __shared__ __align__(16) char smem_raw[40960];
    short* sb = (short*)smem_raw;
    float* sf = (float*)smem_raw;

    const int tid  = threadIdx.x;
    const int lane = tid & 63;
    const int wid  = tid >> 6;
    const int lrow = lane & 15;
    const int kgrp = (lane >> 4) * 8;
    const int m0   = (wid >> 1) * 64;
    const int n0   = (wid & 1) * 64;
    const int r0   = blockIdx.x * 128;
    const int c0   = blockIdx.y * 128;

    const unsigned short* AhT = (const unsigned short*)(ws + WS_AHT);
    const unsigned short* AlT = (const unsigned short*)(ws + WS_ALT);
    const float* c2 = ws + WS_C2;

    const int XH = 0, XL = 5120, BHo = 10240, BLo = 15360;        // shorts
    const int SCT = 0, HT = 4224, W1T = 8448, W2T = 9600, B1O = 10176; // floats

    f32x4 acc[4][4];
#pragma unroll
    for (int mi = 0; mi < 4; ++mi)
#pragma unroll
        for (int ni = 0; ni < 4; ++ni)
#pragma unroll
            for (int rr = 0; rr < 4; ++rr) acc[mi][ni][rr] = 0.f;

    const int r_x = tid >> 1;
    const int k0x = (tid & 1) * 16;
    const float*          xp  = x   + (size_t)(r0 + r_x) * F_DIM + k0x;
    const unsigned short* ahp = AhT + (size_t)(c0 + r_x) * F_DIM + k0x;
    const unsigned short* alp = AlT + (size_t)(c0 + r_x) * F_DIM + k0x;
    short* xh_dst = sb + XH  + r_x * 40 + k0x;
    short* xl_dst = sb + XL  + r_x * 40 + k0x;
    short* bh_dst = sb + BHo + r_x * 40 + k0x;
    short* bl_dst = sb + BLo + r_x * 40 + k0x;

    for (int kc = 0; kc < 256; kc += 32) {
        // stage x chunk: 16 f32 -> bf16 hi/lo (scalarized temps, no local array)
        const float4 v0 = *(const float4*)(xp + kc);
        const float4 v1 = *(const float4*)(xp + kc + 4);
        const float4 v2 = *(const float4*)(xp + kc + 8);
        const float4 v3 = *(const float4*)(xp + kc + 12);
        bf16x8 xh0, xh1, xl0, xl1;
        split4(v0, xh0, xl0, 0);
        split4(v1, xh0, xl0, 4);
        split4(v2, xh1, xl1, 0);
        split4(v3, xh1, xl1, 4);
        *(bf16x8*)(xh_dst)     = xh0;
        *(bf16x8*)(xh_dst + 8) = xh1;
        *(bf16x8*)(xl_dst)     = xl0;
        *(bf16x8*)(xl_dst + 8) = xl1;
        // stage A chunk (already bf16, already transposed)
        *(bf16x8*)(bh_dst)     = *(const bf16x8*)(ahp + kc);
        *(bf16x8*)(bh_dst + 8) = *(const bf16x8*)(ahp + kc + 8);
        *(bf16x8*)(bl_dst)     = *(const bf16x8*)(alp + kc);
        *(bf16x8*)(bl_dst + 8) = *(const bf16x8*)(alp + kc + 8);
        __syncthreads();
        bf16x8 bh[4], bl[4];
#pragma unroll
        for (int ni = 0; ni < 4; ++ni) {
            const int cb = (n0 + ni * 16 + lrow) * 40 + kgrp;
            bh[ni] = *(const bf16x8*)(sb + BHo + cb);
            bl[ni] = *(const bf16x8*)(sb + BLo + cb);
        }
#pragma unroll
        for (int mi = 0; mi < 4; ++mi) {
            const int rb = (m0 + mi * 16 + lrow) * 40 + kgrp;
            const bf16x8 ah = *(const bf16x8*)(sb + XH + rb);
            const bf16x8 al = *(const bf16x8*)(sb + XL + rb);
#pragma unroll
            for (int ni = 0; ni < 4; ++ni) {
                acc[mi][ni] = __builtin_amdgcn_mfma_f32_16x16x32_bf16(ah, bh[ni], acc[mi][ni], 0, 0, 0);
                acc[mi][ni] = __builtin_amdgcn_mfma_f32_16x16x32_bf16(al, bh[ni], acc[mi][ni], 0, 0, 0);
                acc[mi][ni] = __builtin_amdgcn_mfma_f32_16x16x32_bf16(ah, bl[ni], acc[mi][ni], 0, 0, 0);
            }
        }
        __syncthreads();
    }

    // ---- MLP phase ----
    float c2v[4];
#pragma unroll
    for (int ni = 0; ni < 4; ++ni) c2v[ni] = c2[c0 + n0 + ni * 16 + lrow];

    const int tx = tid & 15, ty = tid >> 4;
    float acc3[8];
#pragma unroll
    for (int j = 0; j < 8; ++j) acc3[j] = 0.f;

    // Fully unrolled: acc[mi][(tt&1)*2+q] must be statically indexed (rule #20).
#pragma unroll
    for (int tt = 0; tt < 4; ++tt) {
        const int gt = blockIdx.y * 4 + tt;
        __syncthreads();
        if ((wid & 1) == (tt >> 1)) {
#pragma unroll
            for (int q = 0; q < 2; ++q) {
                const int ni = (tt & 1) * 2 + q;
                const int sl = q * 16 + lrow;
#pragma unroll
                for (int mi = 0; mi < 4; ++mi) {
#pragma unroll
                    for (int rr = 0; rr < 4; ++rr) {
                        const float z = acc[mi][ni][rr] + c2v[ni];
                        sf[SCT + sl * 132 + m0 + mi * 16 + (lane >> 4) * 4 + rr] =
                            1.0f / (1.0f + expf(-z));
                    }
                }
            }
        }
        {
            const float4 v = *(const float4*)&W1g[(size_t)gt * 1024 + tid * 4];
            const int s = tid >> 3, j0 = (tid & 7) * 4;
            sf[W1T + (j0 + 0) * 36 + s] = v.x;
            sf[W1T + (j0 + 1) * 36 + s] = v.y;
            sf[W1T + (j0 + 2) * 36 + s] = v.z;
            sf[W1T + (j0 + 3) * 36 + s] = v.w;
        }
        if (tid < 128) {
            const float4 v = *(const float4*)&W2g[(size_t)gt * 512 + tid * 4];
            const int j = tid >> 2, o0 = (tid & 3) * 4;
            const float sc = 1.0f / (float)T_TREES;
            sf[W2T + (o0 + 0) * 36 + j] = v.x * twg[gt * 16 + o0 + 0] * sc;
            sf[W2T + (o0 + 1) * 36 + j] = v.y * twg[gt * 16 + o0 + 1] * sc;
            sf[W2T + (o0 + 2) * 36 + j] = v.z * twg[gt * 16 + o0 + 2] * sc;
            sf[W2T + (o0 + 3) * 36 + j] = v.w * twg[gt * 16 + o0 + 3] * sc;
        }
        if (tid < 32) sf[B1O + tid] = b1g[gt * 32 + tid];
        __syncthreads();
        // GEMM2
        float a20[8], a21[8];
#pragma unroll
        for (int j = 0; j < 8; ++j) { a20[j] = 0.f; a21[j] = 0.f; }
#pragma unroll
        for (int s4 = 0; s4 < 8; ++s4) {
            const float4 wq0 = *(const float4*)&sf[W1T + (2 * tx) * 36 + s4 * 4];
            const float4 wq1 = *(const float4*)&sf[W1T + (2 * tx + 1) * 36 + s4 * 4];
            const float wa0[4] = {wq0.x, wq0.y, wq0.z, wq0.w};
            const float wa1[4] = {wq1.x, wq1.y, wq1.z, wq1.w};
#pragma unroll
            for (int ss = 0; ss < 4; ++ss) {
                const int s = s4 * 4 + ss;
                const float4 sa0 = *(const float4*)&sf[SCT + s * 132 + ty * 8];
                const float4 sa1 = *(const float4*)&sf[SCT + s * 132 + ty * 8 + 4];
                const float sr[8] = {sa0.x, sa0.y, sa0.z, sa0.w, sa1.x, sa1.y, sa1.z, sa1.w};
#pragma unroll
                for (int j = 0; j < 8; ++j) {
                    a20[j] = fmaf(sr[j], wa0[ss], a20[j]);
                    a21[j] = fmaf(sr[j], wa1[ss], a21[j]);
                }
            }
        }
        const float b1a = sf[B1O + 2 * tx];
        const float b1b = sf[B1O + 2 * tx + 1];
#pragma unroll
        for (int j = 0; j < 8; ++j)
            sf[HT + (2 * tx) * 132 + ty * 8 + j] = fmaxf(a20[j] + b1a, 0.f);
#pragma unroll
        for (int j = 0; j < 8; ++j)
            sf[HT + (2 * tx + 1) * 132 + ty * 8 + j] = fmaxf(a21[j] + b1b, 0.f);
        __syncthreads();
        // GEMM3
#pragma unroll
        for (int j4 = 0; j4 < 8; ++j4) {
            const float4 wq = *(const float4*)&sf[W2T + tx * 36 + j4 * 4];
            const float wa[4] = {wq.x, wq.y, wq.z, wq.w};
#pragma unroll
            for (int u = 0; u < 4; ++u) {
                const int jj = j4 * 4 + u;
                const float4 h0 = *(const float4*)&sf[HT + jj * 132 + ty * 8];
                const float4 h1 = *(const float4*)&sf[HT + jj * 132 + ty * 8 + 4];
                const float hr[8] = {h0.x, h0.y, h0.z, h0.w, h1.x, h1.y, h1.z, h1.w};
#pragma unroll
                for (int j = 0; j < 8; ++j) acc3[j] = fmaf(hr[j], wa[u], acc3[j]);
            }
        }
    }

    if (ATOMIC) {
#pragma unroll
        for (int j = 0; j < 8; ++j)
            atomicAdd(&out[(size_t)(r0 + ty * 8 + j) * 16 + tx], acc3[j]);
    } else {
        float* pp = ws + WS_PART + (size_t)blockIdx.y * (B_ROWS * 16);
#pragma unroll
        for (int j = 0; j < 8; ++j)
            pp[(size_t)(r0 + ty * 8 + j) * 16 + tx] = acc3[j];
    }
}

__global__ void k_reduce(const float* __restrict__ ws, float* __restrict__ out) {
    const int idx = blockIdx.x * 256 + threadIdx.x;
    float s = ws[WS_BIAS + (idx & 15)];
#pragma unroll
    for (int cb = 0; cb < 8; ++cb) s += ws[WS_PART + (size_t)cb * 1048576 + idx];
    out[idx] = s;
}

__global__ void k_init_out(const float* __restrict__ ws, float* __restrict__ out) {
    const int idx = blockIdx.x * 256 + threadIdx.x;
    out[idx] = ws[WS_BIAS + (idx & 15)];
}

extern "C" void kernel_launch(void* const* d_in, const int* in_sizes, int n_in,
                              void* d_out, int out_size, void* d_ws, size_t ws_size,
                              hipStream_t stream) {
    (void)in_sizes; (void)n_in; (void)out_size;
    const float* x     = (const float*)d_in[0];
    const float* gamma = (const float*)d_in[1];
    const float* beta  = (const float*)d_in[2];
    const float* fsm   = (const float*)d_in[3];
    const float* cut   = (const float*)d_in[4];
    const float* W1    = (const float*)d_in[5];
    const float* b1    = (const float*)d_in[6];
    const float* W2    = (const float*)d_in[7];
    const float* b2    = (const float*)d_in[8];
    const float* tw    = (const float*)d_in[9];
    float* out = (float*)d_out;
    float* ws  = (float*)d_ws;

    if (ws_size < (size_t)WS_FLOATS_ATOMIC * sizeof(float)) return;

    const bool partial = ws_size >= (size_t)WS_FLOATS_PARTIAL * sizeof(float);

    k_zero<<<1, 512, 0, stream>>>(ws);
    k_stats<<<512, 256, 0, stream>>>(x, ws);
    k_finalize<<<1, 256, 0, stream>>>(gamma, beta, b2, tw, ws);
    k_sparsemax<<<1024, 256, 0, stream>>>(fsm, cut, ws);
    if (partial) {
        k_main<0><<<dim3(512, 8), 256, 0, stream>>>(x, W1, b1, W2, tw, ws, out);
        k_reduce<<<4096, 256, 0, stream>>>(ws, out);
    } else {
        k_init_out<<<4096, 256, 0, stream>>>(ws, out);
        k_main<1><<<dim3(512, 8), 256, 0, stream>>>(x, W1, b1, W2, tw, ws, out);
    }
}

// Round 8
// 1692.884 us; speedup vs baseline: 1.0563x; 1.0563x over previous
//
#include <hip/hip_runtime.h>
#include <hip/hip_bf16.h>
#include <math.h>

// ---------------------------------------------------------------------------
// CART soft-decision-tree fused pipeline — round 8.
// r6/r7 post-mortem: 4.5 GB/dispatch scratch traffic (spill around K-loop
// MFMAs; live set ~160 > cap). Fix is structural, not launch-bounds:
//   (1) k_splitx pre-splits x -> Xh/Xl bf16 in ws (staging = pure 16B copies)
//   (2) 512-thr blocks, 8 waves, per-wave 32x64 output -> acc = 32 VGPRs
//   (3) K-loop live set ~100 regs under the 128 cap of launch_bounds(512,4)
// Fallbacks if ws_size too small: in-kernel split / atomic-out paths.
// ---------------------------------------------------------------------------

#define B_ROWS 65536
#define F_DIM  256
#define T_TREES 32
#define NC     1024
#define BN_EPS 1e-5f

// ws layout (float offsets)
#define WS_SUM    0
#define WS_SUMSQ  256
#define WS_SCALE  512
#define WS_SHIFT  768
#define WS_BIAS   1024         // 16
#define WS_C2     1040         // 1024
#define WS_AHT    2560         // A^T hi bf16 [1024][256] = 131072 floats
#define WS_ALT    133632       // A^T lo
#define WS_PART   264704       // 8 * 65536*16 = 8388608 floats
#define WS_XH     8653312      // x hi bf16 [65536][256] = 8388608 floats
#define WS_XL     17041920
#define WS_END_FULL 25430528   // 101.7 MB
#define WS_END_PART 8653312    // 34.6 MB
#define WS_END_ATOMIC 264704   // 1.06 MB

typedef __attribute__((ext_vector_type(8))) short bf16x8;
typedef __attribute__((ext_vector_type(4))) float f32x4;

__device__ __forceinline__ void split_bf16(float v, unsigned short& h, unsigned short& l) {
    unsigned u = __builtin_bit_cast(unsigned, v);
    h = (unsigned short)(u >> 16);
    float hf = __builtin_bit_cast(float, (unsigned)h << 16);
    float lo = v - hf;
    l = (unsigned short)(__builtin_bit_cast(unsigned, lo) >> 16);
}

__global__ void k_zero(float* ws) { ws[threadIdx.x] = 0.0f; }

__global__ void k_stats(const float* __restrict__ x, float* __restrict__ ws) {
    const int f  = threadIdx.x;
    const int r0 = blockIdx.x * 128;
    float s = 0.f, sq = 0.f;
    const float* p = x + (size_t)r0 * F_DIM + f;
#pragma unroll 4
    for (int r = 0; r < 128; ++r) { float v = p[(size_t)r * F_DIM]; s += v; sq += v * v; }
    atomicAdd(&ws[WS_SUM  + f], s);
    atomicAdd(&ws[WS_SUMSQ + f], sq);
}

__global__ void k_finalize(const float* __restrict__ gamma, const float* __restrict__ beta,
                           const float* __restrict__ b2, const float* __restrict__ tw,
                           float* __restrict__ ws) {
    const int f = threadIdx.x;
    const float inv = 1.0f / (float)B_ROWS;
    float mean = ws[WS_SUM + f] * inv;
    float var  = ws[WS_SUMSQ + f] * inv - mean * mean;
    float sc   = gamma[f] / sqrtf(var + BN_EPS);
    ws[WS_SCALE + f] = sc;
    ws[WS_SHIFT + f] = beta[f] - mean * sc;
    if (f < 16) {
        float acc = 0.f;
        for (int t = 0; t < T_TREES; ++t) acc += b2[t * 16 + f] * tw[t * 16 + f];
        ws[WS_BIAS + f] = acc * (1.0f / (float)T_TREES);
    }
}

// Pre-split x into bf16 hi/lo streams (same row-major layout as x).
__global__ void k_splitx(const float* __restrict__ x, float* __restrict__ ws) {
    const size_t i8 = ((size_t)blockIdx.x * 256 + threadIdx.x) * 8;
    const float4 a = *(const float4*)(x + i8);
    const float4 b = *(const float4*)(x + i8 + 4);
    bf16x8 hv, lv;
    unsigned short h, l;
    split_bf16(a.x, h, l); hv[0] = (short)h; lv[0] = (short)l;
    split_bf16(a.y, h, l); hv[1] = (short)h; lv[1] = (short)l;
    split_bf16(a.z, h, l); hv[2] = (short)h; lv[2] = (short)l;
    split_bf16(a.w, h, l); hv[3] = (short)h; lv[3] = (short)l;
    split_bf16(b.x, h, l); hv[4] = (short)h; lv[4] = (short)l;
    split_bf16(b.y, h, l); hv[5] = (short)h; lv[5] = (short)l;
    split_bf16(b.z, h, l); hv[6] = (short)h; lv[6] = (short)l;
    split_bf16(b.w, h, l); hv[7] = (short)h; lv[7] = (short)l;
    *(bf16x8*)((unsigned short*)(ws + WS_XH) + i8) = hv;
    *(bf16x8*)((unsigned short*)(ws + WS_XL) + i8) = lv;
}

__global__ void k_sparsemax(const float* __restrict__ fsm, const float* __restrict__ cut,
                            float* __restrict__ ws) {
    __shared__ float zs[256];
    __shared__ float zo[256];
    __shared__ float csA[256];
    __shared__ float csB[256];
    __shared__ float red[256];
    __shared__ int   redi[256];
    const int tid = threadIdx.x;
    const int col = blockIdx.x;           // t*32 + s
    const int t = col >> 5, s = col & 31;
    const float z = fsm[t * 8192 + tid * 32 + s];
    zo[tid] = z;
    zs[tid] = z;
    for (int size = 2; size <= 256; size <<= 1) {
        for (int stride = size >> 1; stride > 0; stride >>= 1) {
            __syncthreads();
            const int p = tid ^ stride;
            const float a = zs[tid], b = zs[p];
            __syncthreads();
            const bool up    = ((tid & size) == 0);
            const bool lower = ((tid & stride) == 0);
            zs[tid] = (lower == up) ? fminf(a, b) : fmaxf(a, b);
        }
    }
    __syncthreads();
    csA[tid] = zs[255 - tid];
    __syncthreads();
    float* src = csA; float* dst = csB;
    for (int off = 1; off < 256; off <<= 1) {
        float v = src[tid];
        if (tid >= off) v += src[tid - off];
        dst[tid] = v;
        __syncthreads();
        float* tmp = src; src = dst; dst = tmp;
    }
    const float zd = zs[255 - tid];
    const float kk = (float)(tid + 1);
    redi[tid] = (1.0f + kk * zd > src[tid]) ? 1 : 0;
    __syncthreads();
    for (int off = 128; off > 0; off >>= 1) {
        if (tid < off) redi[tid] += redi[tid + off];
        __syncthreads();
    }
    const int ksup = redi[0];
    const float tau = (src[ksup - 1] - 1.0f) / (float)ksup;
    const float P = fmaxf(zo[tid] - tau, 0.0f);
    const float av = ws[WS_SCALE + tid] * P;
    unsigned short h, l;
    split_bf16(av, h, l);
    ((unsigned short*)(ws + WS_AHT))[(size_t)col * 256 + tid] = h;
    ((unsigned short*)(ws + WS_ALT))[(size_t)col * 256 + tid] = l;
    red[tid] = ws[WS_SHIFT + tid] * P;
    __syncthreads();
    for (int off = 128; off > 0; off >>= 1) {
        if (tid < off) red[tid] += red[tid + off];
        __syncthreads();
    }
    if (tid == 0) ws[WS_C2 + col] = red[0] - cut[col];
}

// ---------------------------------------------------------------------------
// k_main: 128x128 tile, 512 thr = 8 waves (4m x 2n), per-wave 32x64 output.
// acc[2][4] f32x4 = 32 VGPRs. grid (512, 8).
// LDS (40960 B): K-phase shorts XH@0 XL@5120 BH@10240 BL@15360, rows [*][40].
// MLP floats: SCT@0 [32][132], HT@4224 [32][132], W1T@8448 [32][36],
//   W2T@9600 [16][36], b1@10176.
// ---------------------------------------------------------------------------
template <int ATOMIC, int PRESPLIT>
__global__ __launch_bounds__(512, 4) void k_main(
        const float* __restrict__ x, const float* __restrict__ W1g,
        const float* __restrict__ b1g, const float* __restrict__ W2g,
        const float* __restrict__ twg, float* __restrict__ ws,
        float* __restrict__ out) {
    __shared__ __align__(16) char smem_raw[40960];
    short* sb = (short*)smem_raw;
    float* sf = (float*)smem_raw;

    const int tid  = threadIdx.x;
    const int lane = tid & 63;
    const int wid  = tid >> 6;          // 0..7
    const int lrow = lane & 15;
    const int kgrp = (lane >> 4) * 8;
    const int m0   = (wid >> 1) * 32;   // wave row base
    const int n0   = (wid & 1) * 64;    // wave col base
    const int r0   = blockIdx.x * 128;
    const int c0   = blockIdx.y * 128;

    const unsigned short* AhT = (const unsigned short*)(ws + WS_AHT);
    const unsigned short* AlT = (const unsigned short*)(ws + WS_ALT);
    const unsigned short* XHg = (const unsigned short*)(ws + WS_XH);
    const unsigned short* XLg = (const unsigned short*)(ws + WS_XL);
    const float* c2 = ws + WS_C2;

    const int XH = 0, XL = 5120, BHo = 10240, BLo = 15360;             // shorts
    const int SCT = 0, HT = 4224, W1T = 8448, W2T = 9600, B1O = 10176; // floats

    f32x4 acc[2][4];
#pragma unroll
    for (int mi = 0; mi < 2; ++mi)
#pragma unroll
        for (int ni = 0; ni < 4; ++ni)
#pragma unroll
            for (int rr = 0; rr < 4; ++rr) acc[mi][ni][rr] = 0.f;

    // staging: thread -> (row 0..127, 16B k-quad); 512 thr cover one 8KB tile
    const int r_s = tid >> 2;
    const int kq  = (tid & 3) * 8;
    const size_t xoff = (size_t)(r0 + r_s) * F_DIM + kq;
    const size_t aoff = (size_t)(c0 + r_s) * F_DIM + kq;
    short* xh_dst = sb + XH  + r_s * 40 + kq;
    short* xl_dst = sb + XL  + r_s * 40 + kq;
    short* bh_dst = sb + BHo + r_s * 40 + kq;
    short* bl_dst = sb + BLo + r_s * 40 + kq;

    for (int kc = 0; kc < 256; kc += 32) {
        if (PRESPLIT) {
            *(bf16x8*)xh_dst = *(const bf16x8*)(XHg + xoff + kc);
            *(bf16x8*)xl_dst = *(const bf16x8*)(XLg + xoff + kc);
        } else {
            const float4 a = *(const float4*)(x + xoff + kc);
            const float4 b = *(const float4*)(x + xoff + kc + 4);
            bf16x8 hv, lv;
            unsigned short h, l;
            split_bf16(a.x, h, l); hv[0] = (short)h; lv[0] = (short)l;
            split_bf16(a.y, h, l); hv[1] = (short)h; lv[1] = (short)l;
            split_bf16(a.z, h, l); hv[2] = (short)h; lv[2] = (short)l;
            split_bf16(a.w, h, l); hv[3] = (short)h; lv[3] = (short)l;
            split_bf16(b.x, h, l); hv[4] = (short)h; lv[4] = (short)l;
            split_bf16(b.y, h, l); hv[5] = (short)h; lv[5] = (short)l;
            split_bf16(b.z, h, l); hv[6] = (short)h; lv[6] = (short)l;
            split_bf16(b.w, h, l); hv[7] = (short)h; lv[7] = (short)l;
            *(bf16x8*)xh_dst = hv;
            *(bf16x8*)xl_dst = lv;
        }
        *(bf16x8*)bh_dst = *(const bf16x8*)(AhT + aoff + kc);
        *(bf16x8*)bl_dst = *(const bf16x8*)(AlT + aoff + kc);
        __syncthreads();
        bf16x8 bh[4], bl[4];
#pragma unroll
        for (int ni = 0; ni < 4; ++ni) {
            const int cb = (n0 + ni * 16 + lrow) * 40 + kgrp;
            bh[ni] = *(const bf16x8*)(sb + BHo + cb);
            bl[ni] = *(const bf16x8*)(sb + BLo + cb);
        }
#pragma unroll
        for (int mi = 0; mi < 2; ++mi) {
            const int rb = (m0 + mi * 16 + lrow) * 40 + kgrp;
            const bf16x8 ah = *(const bf16x8*)(sb + XH + rb);
            const bf16x8 al = *(const bf16x8*)(sb + XL + rb);
#pragma unroll
            for (int ni = 0; ni < 4; ++ni) {
                acc[mi][ni] = __builtin_amdgcn_mfma_f32_16x16x32_bf16(ah, bh[ni], acc[mi][ni], 0, 0, 0);
                acc[mi][ni] = __builtin_amdgcn_mfma_f32_16x16x32_bf16(al, bh[ni], acc[mi][ni], 0, 0, 0);
                acc[mi][ni] = __builtin_amdgcn_mfma_f32_16x16x32_bf16(ah, bl[ni], acc[mi][ni], 0, 0, 0);
            }
        }
        __syncthreads();
    }

    // ---- MLP phase ----
    float c2v[4];
#pragma unroll
    for (int ni = 0; ni < 4; ++ni) c2v[ni] = c2[c0 + n0 + ni * 16 + lrow];

    const int tx = tid & 15, ty = tid >> 4;   // 16 x 32 thread grid, 4 rows/thread
    float acc3[4];
#pragma unroll
    for (int j = 0; j < 4; ++j) acc3[j] = 0.f;

#pragma unroll
    for (int tt = 0; tt < 4; ++tt) {
        const int gt = blockIdx.y * 4 + tt;
        __syncthreads();
        // score for tree tt -> SCT[s][132 rows]; waves whose n-half matches
        if ((wid & 1) == (tt >> 1)) {
#pragma unroll
            for (int q = 0; q < 2; ++q) {
                const int ni = (tt & 1) * 2 + q;
                const int sl = q * 16 + lrow;
#pragma unroll
                for (int mi = 0; mi < 2; ++mi) {
#pragma unroll
                    for (int rr = 0; rr < 4; ++rr) {
                        const float z = acc[mi][ni][rr] + c2v[ni];
                        sf[SCT + sl * 132 + m0 + mi * 16 + (lane >> 4) * 4 + rr] =
                            1.0f / (1.0f + expf(-z));
                    }
                }
            }
        }
        if (tid < 256) {
            const float4 v = *(const float4*)&W1g[(size_t)gt * 1024 + tid * 4];
            const int s = tid >> 3, j0 = (tid & 7) * 4;
            sf[W1T + (j0 + 0) * 36 + s] = v.x;
            sf[W1T + (j0 + 1) * 36 + s] = v.y;
            sf[W1T + (j0 + 2) * 36 + s] = v.z;
            sf[W1T + (j0 + 3) * 36 + s] = v.w;
        }
        if (tid < 128) {
            const float4 v = *(const float4*)&W2g[(size_t)gt * 512 + tid * 4];
            const int j = tid >> 2, o0 = (tid & 3) * 4;
            const float sc = 1.0f / (float)T_TREES;
            sf[W2T + (o0 + 0) * 36 + j] = v.x * twg[gt * 16 + o0 + 0] * sc;
            sf[W2T + (o0 + 1) * 36 + j] = v.y * twg[gt * 16 + o0 + 1] * sc;
            sf[W2T + (o0 + 2) * 36 + j] = v.z * twg[gt * 16 + o0 + 2] * sc;
            sf[W2T + (o0 + 3) * 36 + j] = v.w * twg[gt * 16 + o0 + 3] * sc;
        }
        if (tid < 32) sf[B1O + tid] = b1g[gt * 32 + tid];
        __syncthreads();
        // GEMM2: h[r][2tx], h[r][2tx+1] for 4 rows r = ty*4..+4
        float a20[4], a21[4];
#pragma unroll
        for (int j = 0; j < 4; ++j) { a20[j] = 0.f; a21[j] = 0.f; }
#pragma unroll
        for (int s4 = 0; s4 < 8; ++s4) {
            const float4 wq0 = *(const float4*)&sf[W1T + (2 * tx) * 36 + s4 * 4];
            const float4 wq1 = *(const float4*)&sf[W1T + (2 * tx + 1) * 36 + s4 * 4];
            const float wa0[4] = {wq0.x, wq0.y, wq0.z, wq0.w};
            const float wa1[4] = {wq1.x, wq1.y, wq1.z, wq1.w};
#pragma unroll
            for (int ss = 0; ss < 4; ++ss) {
                const int s = s4 * 4 + ss;
                const float4 sa = *(const float4*)&sf[SCT + s * 132 + ty * 4];
                const float sr[4] = {sa.x, sa.y, sa.z, sa.w};
#pragma unroll
                for (int j = 0; j < 4; ++j) {
                    a20[j] = fmaf(sr[j], wa0[ss], a20[j]);
                    a21[j] = fmaf(sr[j], wa1[ss], a21[j]);
                }
            }
        }
        const float b1a = sf[B1O + 2 * tx];
        const float b1b = sf[B1O + 2 * tx + 1];
#pragma unroll
        for (int j = 0; j < 4; ++j)
            sf[HT + (2 * tx) * 132 + ty * 4 + j] = fmaxf(a20[j] + b1a, 0.f);
#pragma unroll
        for (int j = 0; j < 4; ++j)
            sf[HT + (2 * tx + 1) * 132 + ty * 4 + j] = fmaxf(a21[j] + b1b, 0.f);
        __syncthreads();
        // GEMM3: o = tx
#pragma unroll
        for (int j4 = 0; j4 < 8; ++j4) {
            const float4 wq = *(const float4*)&sf[W2T + tx * 36 + j4 * 4];
            const float wa[4] = {wq.x, wq.y, wq.z, wq.w};
#pragma unroll
            for (int u = 0; u < 4; ++u) {
                const int jj = j4 * 4 + u;
                const float4 h0 = *(const float4*)&sf[HT + jj * 132 + ty * 4];
                const float hr[4] = {h0.x, h0.y, h0.z, h0.w};
#pragma unroll
                for (int j = 0; j < 4; ++j) acc3[j] = fmaf(hr[j], wa[u], acc3[j]);
            }
        }
    }

    if (ATOMIC) {
#pragma unroll
        for (int j = 0; j < 4; ++j)
            atomicAdd(&out[(size_t)(r0 + ty * 4 + j) * 16 + tx], acc3[j]);
    } else {
        float* pp = ws + WS_PART + (size_t)blockIdx.y * (B_ROWS * 16);
#pragma unroll
        for (int j = 0; j < 4; ++j)
            pp[(size_t)(r0 + ty * 4 + j) * 16 + tx] = acc3[j];
    }
}

__global__ void k_reduce(const float* __restrict__ ws, float* __restrict__ out) {
    const int idx = blockIdx.x * 256 + threadIdx.x;
    float s = ws[WS_BIAS + (idx & 15)];
#pragma unroll
    for (int cb = 0; cb < 8; ++cb) s += ws[WS_PART + (size_t)cb * 1048576 + idx];
    out[idx] = s;
}

__global__ void k_init_out(const float* __restrict__ ws, float* __restrict__ out) {
    const int idx = blockIdx.x * 256 + threadIdx.x;
    out[idx] = ws[WS_BIAS + (idx & 15)];
}

extern "C" void kernel_launch(void* const* d_in, const int* in_sizes, int n_in,
                              void* d_out, int out_size, void* d_ws, size_t ws_size,
                              hipStream_t stream) {
    (void)in_sizes; (void)n_in; (void)out_size;
    const float* x     = (const float*)d_in[0];
    const float* gamma = (const float*)d_in[1];
    const float* beta  = (const float*)d_in[2];
    const float* fsm   = (const float*)d_in[3];
    const float* cut   = (const float*)d_in[4];
    const float* W1    = (const float*)d_in[5];
    const float* b1    = (const float*)d_in[6];
    const float* W2    = (const float*)d_in[7];
    const float* b2    = (const float*)d_in[8];
    const float* tw    = (const float*)d_in[9];
    float* out = (float*)d_out;
    float* ws  = (float*)d_ws;

    if (ws_size < (size_t)WS_END_ATOMIC * sizeof(float)) return;  // clean fail

    k_zero<<<1, 512, 0, stream>>>(ws);
    k_stats<<<512, 256, 0, stream>>>(x, ws);
    k_finalize<<<1, 256, 0, stream>>>(gamma, beta, b2, tw, ws);
    k_sparsemax<<<1024, 256, 0, stream>>>(fsm, cut, ws);

    if (ws_size >= (size_t)WS_END_FULL * sizeof(float)) {
        k_splitx<<<8192, 256, 0, stream>>>(x, ws);
        k_main<0, 1><<<dim3(512, 8), 512, 0, stream>>>(x, W1, b1, W2, tw, ws, out);
        k_reduce<<<4096, 256, 0, stream>>>(ws, out);
    } else if (ws_size >= (size_t)WS_END_PART * sizeof(float)) {
        k_main<0, 0><<<dim3(512, 8), 512, 0, stream>>>(x, W1, b1, W2, tw, ws, out);
        k_reduce<<<4096, 256, 0, stream>>>(ws, out);
    } else {
        k_init_out<<<4096, 256, 0, stream>>>(ws, out);
        k_main<1, 0><<<dim3(512, 8), 512, 0, stream>>>(x, W1, b1, W2, tw, ws, out);
    }
}

// Round 9
// 1134.057 us; speedup vs baseline: 1.5768x; 1.4928x over previous
//
#include <hip/hip_runtime.h>
#include <hip/hip_bf16.h>
#include <math.h>

// ---------------------------------------------------------------------------
// CART soft-decision-tree fused pipeline — round 9.
// r6-r8 post-mortem: VGPR_Count tracked 512/(backend-target waves/SIMD)
// (84/128/64) — every launch_bounds choice LOWERED the register cap below the
// K-loop live set (~100-130), forcing spill-around-MFMA => stable ~5 GB/dispatch
// scratch traffic. r9 single-variable fix: __launch_bounds__(512, 1) => cap 256
// under both arg2 interpretations. Everything else identical to r8.
// ---------------------------------------------------------------------------

#define B_ROWS 65536
#define F_DIM  256
#define T_TREES 32
#define NC     1024
#define BN_EPS 1e-5f

// ws layout (float offsets)
#define WS_SUM    0
#define WS_SUMSQ  256
#define WS_SCALE  512
#define WS_SHIFT  768
#define WS_BIAS   1024         // 16
#define WS_C2     1040         // 1024
#define WS_AHT    2560         // A^T hi bf16 [1024][256] = 131072 floats
#define WS_ALT    133632       // A^T lo
#define WS_PART   264704       // 8 * 65536*16 = 8388608 floats
#define WS_XH     8653312      // x hi bf16 [65536][256] = 8388608 floats
#define WS_XL     17041920
#define WS_END_FULL 25430528   // 101.7 MB
#define WS_END_PART 8653312    // 34.6 MB
#define WS_END_ATOMIC 264704   // 1.06 MB

typedef __attribute__((ext_vector_type(8))) short bf16x8;
typedef __attribute__((ext_vector_type(4))) float f32x4;

__device__ __forceinline__ void split_bf16(float v, unsigned short& h, unsigned short& l) {
    unsigned u = __builtin_bit_cast(unsigned, v);
    h = (unsigned short)(u >> 16);
    float hf = __builtin_bit_cast(float, (unsigned)h << 16);
    float lo = v - hf;
    l = (unsigned short)(__builtin_bit_cast(unsigned, lo) >> 16);
}

__global__ void k_zero(float* ws) { ws[threadIdx.x] = 0.0f; }

__global__ void k_stats(const float* __restrict__ x, float* __restrict__ ws) {
    const int f  = threadIdx.x;
    const int r0 = blockIdx.x * 128;
    float s = 0.f, sq = 0.f;
    const float* p = x + (size_t)r0 * F_DIM + f;
#pragma unroll 4
    for (int r = 0; r < 128; ++r) { float v = p[(size_t)r * F_DIM]; s += v; sq += v * v; }
    atomicAdd(&ws[WS_SUM  + f], s);
    atomicAdd(&ws[WS_SUMSQ + f], sq);
}

__global__ void k_finalize(const float* __restrict__ gamma, const float* __restrict__ beta,
                           const float* __restrict__ b2, const float* __restrict__ tw,
                           float* __restrict__ ws) {
    const int f = threadIdx.x;
    const float inv = 1.0f / (float)B_ROWS;
    float mean = ws[WS_SUM + f] * inv;
    float var  = ws[WS_SUMSQ + f] * inv - mean * mean;
    float sc   = gamma[f] / sqrtf(var + BN_EPS);
    ws[WS_SCALE + f] = sc;
    ws[WS_SHIFT + f] = beta[f] - mean * sc;
    if (f < 16) {
        float acc = 0.f;
        for (int t = 0; t < T_TREES; ++t) acc += b2[t * 16 + f] * tw[t * 16 + f];
        ws[WS_BIAS + f] = acc * (1.0f / (float)T_TREES);
    }
}

// Pre-split x into bf16 hi/lo streams (same row-major layout as x).
__global__ void k_splitx(const float* __restrict__ x, float* __restrict__ ws) {
    const size_t i8 = ((size_t)blockIdx.x * 256 + threadIdx.x) * 8;
    const float4 a = *(const float4*)(x + i8);
    const float4 b = *(const float4*)(x + i8 + 4);
    bf16x8 hv, lv;
    unsigned short h, l;
    split_bf16(a.x, h, l); hv[0] = (short)h; lv[0] = (short)l;
    split_bf16(a.y, h, l); hv[1] = (short)h; lv[1] = (short)l;
    split_bf16(a.z, h, l); hv[2] = (short)h; lv[2] = (short)l;
    split_bf16(a.w, h, l); hv[3] = (short)h; lv[3] = (short)l;
    split_bf16(b.x, h, l); hv[4] = (short)h; lv[4] = (short)l;
    split_bf16(b.y, h, l); hv[5] = (short)h; lv[5] = (short)l;
    split_bf16(b.z, h, l); hv[6] = (short)h; lv[6] = (short)l;
    split_bf16(b.w, h, l); hv[7] = (short)h; lv[7] = (short)l;
    *(bf16x8*)((unsigned short*)(ws + WS_XH) + i8) = hv;
    *(bf16x8*)((unsigned short*)(ws + WS_XL) + i8) = lv;
}

__global__ void k_sparsemax(const float* __restrict__ fsm, const float* __restrict__ cut,
                            float* __restrict__ ws) {
    __shared__ float zs[256];
    __shared__ float zo[256];
    __shared__ float csA[256];
    __shared__ float csB[256];
    __shared__ float red[256];
    __shared__ int   redi[256];
    const int tid = threadIdx.x;
    const int col = blockIdx.x;           // t*32 + s
    const int t = col >> 5, s = col & 31;
    const float z = fsm[t * 8192 + tid * 32 + s];
    zo[tid] = z;
    zs[tid] = z;
    for (int size = 2; size <= 256; size <<= 1) {
        for (int stride = size >> 1; stride > 0; stride >>= 1) {
            __syncthreads();
            const int p = tid ^ stride;
            const float a = zs[tid], b = zs[p];
            __syncthreads();
            const bool up    = ((tid & size) == 0);
            const bool lower = ((tid & stride) == 0);
            zs[tid] = (lower == up) ? fminf(a, b) : fmaxf(a, b);
        }
    }
    __syncthreads();
    csA[tid] = zs[255 - tid];
    __syncthreads();
    float* src = csA; float* dst = csB;
    for (int off = 1; off < 256; off <<= 1) {
        float v = src[tid];
        if (tid >= off) v += src[tid - off];
        dst[tid] = v;
        __syncthreads();
        float* tmp = src; src = dst; dst = tmp;
    }
    const float zd = zs[255 - tid];
    const float kk = (float)(tid + 1);
    redi[tid] = (1.0f + kk * zd > src[tid]) ? 1 : 0;
    __syncthreads();
    for (int off = 128; off > 0; off >>= 1) {
        if (tid < off) redi[tid] += redi[tid + off];
        __syncthreads();
    }
    const int ksup = redi[0];
    const float tau = (src[ksup - 1] - 1.0f) / (float)ksup;
    const float P = fmaxf(zo[tid] - tau, 0.0f);
    const float av = ws[WS_SCALE + tid] * P;
    unsigned short h, l;
    split_bf16(av, h, l);
    ((unsigned short*)(ws + WS_AHT))[(size_t)col * 256 + tid] = h;
    ((unsigned short*)(ws + WS_ALT))[(size_t)col * 256 + tid] = l;
    red[tid] = ws[WS_SHIFT + tid] * P;
    __syncthreads();
    for (int off = 128; off > 0; off >>= 1) {
        if (tid < off) red[tid] += red[tid + off];
        __syncthreads();
    }
    if (tid == 0) ws[WS_C2 + col] = red[0] - cut[col];
}

// ---------------------------------------------------------------------------
// k_main: 128x128 tile, 512 thr = 8 waves (4m x 2n), per-wave 32x64 output.
// acc[2][4] f32x4 = 32 VGPRs. grid (512, 8).
// LDS (40960 B): K-phase shorts XH@0 XL@5120 BH@10240 BL@15360, rows [*][40].
// MLP floats: SCT@0 [32][132], HT@4224 [32][132], W1T@8448 [32][36],
//   W2T@9600 [16][36], b1@10176.
// launch_bounds(512, 1): promise minimal occupancy -> VGPR cap 256 (r6-r8:
// backend targeted LDS-implied occupancy, capped VGPRs at 64-128 < live set,
// spilled the K-loop to scratch -> 5 GB/dispatch HBM traffic).
// ---------------------------------------------------------------------------
template <int ATOMIC, int PRESPLIT>
__global__ __launch_bounds__(512, 1) void k_main(
        const float* __restrict__ x, const float* __restrict__ W1g,
        const float* __restrict__ b1g, const float* __restrict__ W2g,
        const float* __restrict__ twg, float* __restrict__ ws,
        float* __restrict__ out) {
    __shared__ __align__(16) char smem_raw[40960];
    short* sb = (short*)smem_raw;
    float* sf = (float*)smem_raw;

    const int tid  = threadIdx.x;
    const int lane = tid & 63;
    const int wid  = tid >> 6;          // 0..7
    const int lrow = lane & 15;
    const int kgrp = (lane >> 4) * 8;
    const int m0   = (wid >> 1) * 32;   // wave row base
    const int n0   = (wid & 1) * 64;    // wave col base
    const int r0   = blockIdx.x * 128;
    const int c0   = blockIdx.y * 128;

    const unsigned short* AhT = (const unsigned short*)(ws + WS_AHT);
    const unsigned short* AlT = (const unsigned short*)(ws + WS_ALT);
    const unsigned short* XHg = (const unsigned short*)(ws + WS_XH);
    const unsigned short* XLg = (const unsigned short*)(ws + WS_XL);
    const float* c2 = ws + WS_C2;

    const int XH = 0, XL = 5120, BHo = 10240, BLo = 15360;             // shorts
    const int SCT = 0, HT = 4224, W1T = 8448, W2T = 9600, B1O = 10176; // floats

    f32x4 acc[2][4];
#pragma unroll
    for (int mi = 0; mi < 2; ++mi)
#pragma unroll
        for (int ni = 0; ni < 4; ++ni)
#pragma unroll
            for (int rr = 0; rr < 4; ++rr) acc[mi][ni][rr] = 0.f;

    // staging: thread -> (row 0..127, 16B k-quad); 512 thr cover one 8KB tile
    const int r_s = tid >> 2;
    const int kq  = (tid & 3) * 8;
    const size_t xoff = (size_t)(r0 + r_s) * F_DIM + kq;
    const size_t aoff = (size_t)(c0 + r_s) * F_DIM + kq;
    short* xh_dst = sb + XH  + r_s * 40 + kq;
    short* xl_dst = sb + XL  + r_s * 40 + kq;
    short* bh_dst = sb + BHo + r_s * 40 + kq;
    short* bl_dst = sb + BLo + r_s * 40 + kq;

    for (int kc = 0; kc < 256; kc += 32) {
        if (PRESPLIT) {
            *(bf16x8*)xh_dst = *(const bf16x8*)(XHg + xoff + kc);
            *(bf16x8*)xl_dst = *(const bf16x8*)(XLg + xoff + kc);
        } else {
            const float4 a = *(const float4*)(x + xoff + kc);
            const float4 b = *(const float4*)(x + xoff + kc + 4);
            bf16x8 hv, lv;
            unsigned short h, l;
            split_bf16(a.x, h, l); hv[0] = (short)h; lv[0] = (short)l;
            split_bf16(a.y, h, l); hv[1] = (short)h; lv[1] = (short)l;
            split_bf16(a.z, h, l); hv[2] = (short)h; lv[2] = (short)l;
            split_bf16(a.w, h, l); hv[3] = (short)h; lv[3] = (short)l;
            split_bf16(b.x, h, l); hv[4] = (short)h; lv[4] = (short)l;
            split_bf16(b.y, h, l); hv[5] = (short)h; lv[5] = (short)l;
            split_bf16(b.z, h, l); hv[6] = (short)h; lv[6] = (short)l;
            split_bf16(b.w, h, l); hv[7] = (short)h; lv[7] = (short)l;
            *(bf16x8*)xh_dst = hv;
            *(bf16x8*)xl_dst = lv;
        }
        *(bf16x8*)bh_dst = *(const bf16x8*)(AhT + aoff + kc);
        *(bf16x8*)bl_dst = *(const bf16x8*)(AlT + aoff + kc);
        __syncthreads();
        bf16x8 bh[4], bl[4];
#pragma unroll
        for (int ni = 0; ni < 4; ++ni) {
            const int cb = (n0 + ni * 16 + lrow) * 40 + kgrp;
            bh[ni] = *(const bf16x8*)(sb + BHo + cb);
            bl[ni] = *(const bf16x8*)(sb + BLo + cb);
        }
#pragma unroll
        for (int mi = 0; mi < 2; ++mi) {
            const int rb = (m0 + mi * 16 + lrow) * 40 + kgrp;
            const bf16x8 ah = *(const bf16x8*)(sb + XH + rb);
            const bf16x8 al = *(const bf16x8*)(sb + XL + rb);
#pragma unroll
            for (int ni = 0; ni < 4; ++ni) {
                acc[mi][ni] = __builtin_amdgcn_mfma_f32_16x16x32_bf16(ah, bh[ni], acc[mi][ni], 0, 0, 0);
                acc[mi][ni] = __builtin_amdgcn_mfma_f32_16x16x32_bf16(al, bh[ni], acc[mi][ni], 0, 0, 0);
                acc[mi][ni] = __builtin_amdgcn_mfma_f32_16x16x32_bf16(ah, bl[ni], acc[mi][ni], 0, 0, 0);
            }
        }
        __syncthreads();
    }

    // ---- MLP phase ----
    float c2v[4];
#pragma unroll
    for (int ni = 0; ni < 4; ++ni) c2v[ni] = c2[c0 + n0 + ni * 16 + lrow];

    const int tx = tid & 15, ty = tid >> 4;   // 16 x 32 thread grid, 4 rows/thread
    float acc3[4];
#pragma unroll
    for (int j = 0; j < 4; ++j) acc3[j] = 0.f;

#pragma unroll
    for (int tt = 0; tt < 4; ++tt) {
        const int gt = blockIdx.y * 4 + tt;
        __syncthreads();
        // score for tree tt -> SCT[s][132 rows]; waves whose n-half matches
        if ((wid & 1) == (tt >> 1)) {
#pragma unroll
            for (int q = 0; q < 2; ++q) {
                const int ni = (tt & 1) * 2 + q;
                const int sl = q * 16 + lrow;
#pragma unroll
                for (int mi = 0; mi < 2; ++mi) {
#pragma unroll
                    for (int rr = 0; rr < 4; ++rr) {
                        const float z = acc[mi][ni][rr] + c2v[ni];
                        sf[SCT + sl * 132 + m0 + mi * 16 + (lane >> 4) * 4 + rr] =
                            1.0f / (1.0f + expf(-z));
                    }
                }
            }
        }
        if (tid < 256) {
            const float4 v = *(const float4*)&W1g[(size_t)gt * 1024 + tid * 4];
            const int s = tid >> 3, j0 = (tid & 7) * 4;
            sf[W1T + (j0 + 0) * 36 + s] = v.x;
            sf[W1T + (j0 + 1) * 36 + s] = v.y;
            sf[W1T + (j0 + 2) * 36 + s] = v.z;
            sf[W1T + (j0 + 3) * 36 + s] = v.w;
        }
        if (tid < 128) {
            const float4 v = *(const float4*)&W2g[(size_t)gt * 512 + tid * 4];
            const int j = tid >> 2, o0 = (tid & 3) * 4;
            const float sc = 1.0f / (float)T_TREES;
            sf[W2T + (o0 + 0) * 36 + j] = v.x * twg[gt * 16 + o0 + 0] * sc;
            sf[W2T + (o0 + 1) * 36 + j] = v.y * twg[gt * 16 + o0 + 1] * sc;
            sf[W2T + (o0 + 2) * 36 + j] = v.z * twg[gt * 16 + o0 + 2] * sc;
            sf[W2T + (o0 + 3) * 36 + j] = v.w * twg[gt * 16 + o0 + 3] * sc;
        }
        if (tid < 32) sf[B1O + tid] = b1g[gt * 32 + tid];
        __syncthreads();
        // GEMM2: h[r][2tx], h[r][2tx+1] for 4 rows r = ty*4..+4
        float a20[4], a21[4];
#pragma unroll
        for (int j = 0; j < 4; ++j) { a20[j] = 0.f; a21[j] = 0.f; }
#pragma unroll
        for (int s4 = 0; s4 < 8; ++s4) {
            const float4 wq0 = *(const float4*)&sf[W1T + (2 * tx) * 36 + s4 * 4];
            const float4 wq1 = *(const float4*)&sf[W1T + (2 * tx + 1) * 36 + s4 * 4];
            const float wa0[4] = {wq0.x, wq0.y, wq0.z, wq0.w};
            const float wa1[4] = {wq1.x, wq1.y, wq1.z, wq1.w};
#pragma unroll
            for (int ss = 0; ss < 4; ++ss) {
                const int s = s4 * 4 + ss;
                const float4 sa = *(const float4*)&sf[SCT + s * 132 + ty * 4];
                const float sr[4] = {sa.x, sa.y, sa.z, sa.w};
#pragma unroll
                for (int j = 0; j < 4; ++j) {
                    a20[j] = fmaf(sr[j], wa0[ss], a20[j]);
                    a21[j] = fmaf(sr[j], wa1[ss], a21[j]);
                }
            }
        }
        const float b1a = sf[B1O + 2 * tx];
        const float b1b = sf[B1O + 2 * tx + 1];
#pragma unroll
        for (int j = 0; j < 4; ++j)
            sf[HT + (2 * tx) * 132 + ty * 4 + j] = fmaxf(a20[j] + b1a, 0.f);
#pragma unroll
        for (int j = 0; j < 4; ++j)
            sf[HT + (2 * tx + 1) * 132 + ty * 4 + j] = fmaxf(a21[j] + b1b, 0.f);
        __syncthreads();
        // GEMM3: o = tx
#pragma unroll
        for (int j4 = 0; j4 < 8; ++j4) {
            const float4 wq = *(const float4*)&sf[W2T + tx * 36 + j4 * 4];
            const float wa[4] = {wq.x, wq.y, wq.z, wq.w};
#pragma unroll
            for (int u = 0; u < 4; ++u) {
                const int jj = j4 * 4 + u;
                const float4 h0 = *(const float4*)&sf[HT + jj * 132 + ty * 4];
                const float hr[4] = {h0.x, h0.y, h0.z, h0.w};
#pragma unroll
                for (int j = 0; j < 4; ++j) acc3[j] = fmaf(hr[j], wa[u], acc3[j]);
            }
        }
    }

    if (ATOMIC) {
#pragma unroll
        for (int j = 0; j < 4; ++j)
            atomicAdd(&out[(size_t)(r0 + ty * 4 + j) * 16 + tx], acc3[j]);
    } else {
        float* pp = ws + WS_PART + (size_t)blockIdx.y * (B_ROWS * 16);
#pragma unroll
        for (int j = 0; j < 4; ++j)
            pp[(size_t)(r0 + ty * 4 + j) * 16 + tx] = acc3[j];
    }
}

__global__ void k_reduce(const float* __restrict__ ws, float* __restrict__ out) {
    const int idx = blockIdx.x * 256 + threadIdx.x;
    float s = ws[WS_BIAS + (idx & 15)];
#pragma unroll
    for (int cb = 0; cb < 8; ++cb) s += ws[WS_PART + (size_t)cb * 1048576 + idx];
    out[idx] = s;
}

__global__ void k_init_out(const float* __restrict__ ws, float* __restrict__ out) {
    const int idx = blockIdx.x * 256 + threadIdx.x;
    out[idx] = ws[WS_BIAS + (idx & 15)];
}

extern "C" void kernel_launch(void* const* d_in, const int* in_sizes, int n_in,
                              void* d_out, int out_size, void* d_ws, size_t ws_size,
                              hipStream_t stream) {
    (void)in_sizes; (void)n_in; (void)out_size;
    const float* x     = (const float*)d_in[0];
    const float* gamma = (const float*)d_in[1];
    const float* beta  = (const float*)d_in[2];
    const float* fsm   = (const float*)d_in[3];
    const float* cut   = (const float*)d_in[4];
    const float* W1    = (const float*)d_in[5];
    const float* b1    = (const float*)d_in[6];
    const float* W2    = (const float*)d_in[7];
    const float* b2    = (const float*)d_in[8];
    const float* tw    = (const float*)d_in[9];
    float* out = (float*)d_out;
    float* ws  = (float*)d_ws;

    if (ws_size < (size_t)WS_END_ATOMIC * sizeof(float)) return;  // clean fail

    k_zero<<<1, 512, 0, stream>>>(ws);
    k_stats<<<512, 256, 0, stream>>>(x, ws);
    k_finalize<<<1, 256, 0, stream>>>(gamma, beta, b2, tw, ws);
    k_sparsemax<<<1024, 256, 0, stream>>>(fsm, cut, ws);

    if (ws_size >= (size_t)WS_END_FULL * sizeof(float)) {
        k_splitx<<<8192, 256, 0, stream>>>(x, ws);
        k_main<0, 1><<<dim3(512, 8), 512, 0, stream>>>(x, W1, b1, W2, tw, ws, out);
        k_reduce<<<4096, 256, 0, stream>>>(ws, out);
    } else if (ws_size >= (size_t)WS_END_PART * sizeof(float)) {
        k_main<0, 0><<<dim3(512, 8), 512, 0, stream>>>(x, W1, b1, W2, tw, ws, out);
        k_reduce<<<4096, 256, 0, stream>>>(ws, out);
    } else {
        k_init_out<<<4096, 256, 0, stream>>>(ws, out);
        k_main<1, 0><<<dim3(512, 8), 512, 0, stream>>>(x, W1, b1, W2, tw, ws, out);
    }
}

// Round 10
// 506.615 us; speedup vs baseline: 3.5297x; 2.2385x over previous
//
#include <hip/hip_runtime.h>
#include <hip/hip_bf16.h>
#include <math.h>

// ---------------------------------------------------------------------------
// CART pipeline — round 10: DECOMPOSED. r6-r9's fused k_main never stopped
// spilling (WRITE_SIZE 2.2-3.2 GB vs 34 MB legit). Split into:
//   k_gemm1: MFMA bf16-split GEMM -> sigmoid -> score fp16 (materialized)
//   k_mlp:   per-row tree MLPs from score, weights broadcast from LDS
// Each kernel's live set fits any VGPR cap. Score round-trip costs ~75 us.
// Fallback paths (fused r9 kernel) kept for small ws_size.
// ---------------------------------------------------------------------------

#define B_ROWS 65536
#define F_DIM  256
#define T_TREES 32
#define NC     1024
#define BN_EPS 1e-5f

// ws layout (float offsets)
#define WS_SUM    0
#define WS_SUMSQ  256
#define WS_SCALE  512
#define WS_SHIFT  768
#define WS_BIAS   1024
#define WS_C2     1040
#define WS_AHT    2560          // A^T hi bf16 [1024][256]
#define WS_ALT    133632        // A^T lo
#define WS_BASE_END 264704
// decomposed paths:
#define WS_SCORE  264704        // fp16 [32][65536][32] = 33554432 float-units
#define WS_MID_END 33819136     // 135.3 MB
#define WS_XH2    33819136      // x hi bf16 [65536][256]
#define WS_XL2    42207744
#define WS_FULL_END 50596352    // 202.4 MB
// fused-fallback partials (overlaps WS_SCORE; paths exclusive):
#define WS_PART   264704
#define WS_PART_END 8653312     // 34.6 MB

typedef __attribute__((ext_vector_type(8))) short bf16x8;
typedef __attribute__((ext_vector_type(4))) float f32x4;
typedef _Float16 half8 __attribute__((ext_vector_type(8)));

__device__ __forceinline__ void split_bf16(float v, unsigned short& h, unsigned short& l) {
    unsigned u = __builtin_bit_cast(unsigned, v);
    h = (unsigned short)(u >> 16);
    float hf = __builtin_bit_cast(float, (unsigned)h << 16);
    float lo = v - hf;
    l = (unsigned short)(__builtin_bit_cast(unsigned, lo) >> 16);
}

__global__ void k_zero(float* ws) { ws[threadIdx.x] = 0.0f; }

__global__ void k_stats(const float* __restrict__ x, float* __restrict__ ws) {
    const int f  = threadIdx.x;
    const int r0 = blockIdx.x * 128;
    float s = 0.f, sq = 0.f;
    const float* p = x + (size_t)r0 * F_DIM + f;
#pragma unroll 4
    for (int r = 0; r < 128; ++r) { float v = p[(size_t)r * F_DIM]; s += v; sq += v * v; }
    atomicAdd(&ws[WS_SUM  + f], s);
    atomicAdd(&ws[WS_SUMSQ + f], sq);
}

__global__ void k_finalize(const float* __restrict__ gamma, const float* __restrict__ beta,
                           const float* __restrict__ b2, const float* __restrict__ tw,
                           float* __restrict__ ws) {
    const int f = threadIdx.x;
    const float inv = 1.0f / (float)B_ROWS;
    float mean = ws[WS_SUM + f] * inv;
    float var  = ws[WS_SUMSQ + f] * inv - mean * mean;
    float sc   = gamma[f] / sqrtf(var + BN_EPS);
    ws[WS_SCALE + f] = sc;
    ws[WS_SHIFT + f] = beta[f] - mean * sc;
    if (f < 16) {
        float acc = 0.f;
        for (int t = 0; t < T_TREES; ++t) acc += b2[t * 16 + f] * tw[t * 16 + f];
        ws[WS_BIAS + f] = acc * (1.0f / (float)T_TREES);
    }
}

__global__ void k_splitx(const float* __restrict__ x, float* __restrict__ ws) {
    const size_t i8 = ((size_t)blockIdx.x * 256 + threadIdx.x) * 8;
    const float4 a = *(const float4*)(x + i8);
    const float4 b = *(const float4*)(x + i8 + 4);
    bf16x8 hv, lv;
    unsigned short h, l;
    split_bf16(a.x, h, l); hv[0] = (short)h; lv[0] = (short)l;
    split_bf16(a.y, h, l); hv[1] = (short)h; lv[1] = (short)l;
    split_bf16(a.z, h, l); hv[2] = (short)h; lv[2] = (short)l;
    split_bf16(a.w, h, l); hv[3] = (short)h; lv[3] = (short)l;
    split_bf16(b.x, h, l); hv[4] = (short)h; lv[4] = (short)l;
    split_bf16(b.y, h, l); hv[5] = (short)h; lv[5] = (short)l;
    split_bf16(b.z, h, l); hv[6] = (short)h; lv[6] = (short)l;
    split_bf16(b.w, h, l); hv[7] = (short)h; lv[7] = (short)l;
    *(bf16x8*)((unsigned short*)(ws + WS_XH2) + i8) = hv;
    *(bf16x8*)((unsigned short*)(ws + WS_XL2) + i8) = lv;
}

__global__ void k_sparsemax(const float* __restrict__ fsm, const float* __restrict__ cut,
                            float* __restrict__ ws) {
    __shared__ float zs[256];
    __shared__ float zo[256];
    __shared__ float csA[256];
    __shared__ float csB[256];
    __shared__ float red[256];
    __shared__ int   redi[256];
    const int tid = threadIdx.x;
    const int col = blockIdx.x;
    const int t = col >> 5, s = col & 31;
    const float z = fsm[t * 8192 + tid * 32 + s];
    zo[tid] = z;
    zs[tid] = z;
    for (int size = 2; size <= 256; size <<= 1) {
        for (int stride = size >> 1; stride > 0; stride >>= 1) {
            __syncthreads();
            const int p = tid ^ stride;
            const float a = zs[tid], b = zs[p];
            __syncthreads();
            const bool up    = ((tid & size) == 0);
            const bool lower = ((tid & stride) == 0);
            zs[tid] = (lower == up) ? fminf(a, b) : fmaxf(a, b);
        }
    }
    __syncthreads();
    csA[tid] = zs[255 - tid];
    __syncthreads();
    float* src = csA; float* dst = csB;
    for (int off = 1; off < 256; off <<= 1) {
        float v = src[tid];
        if (tid >= off) v += src[tid - off];
        dst[tid] = v;
        __syncthreads();
        float* tmp = src; src = dst; dst = tmp;
    }
    const float zd = zs[255 - tid];
    const float kk = (float)(tid + 1);
    redi[tid] = (1.0f + kk * zd > src[tid]) ? 1 : 0;
    __syncthreads();
    for (int off = 128; off > 0; off >>= 1) {
        if (tid < off) redi[tid] += redi[tid + off];
        __syncthreads();
    }
    const int ksup = redi[0];
    const float tau = (src[ksup - 1] - 1.0f) / (float)ksup;
    const float P = fmaxf(zo[tid] - tau, 0.0f);
    const float av = ws[WS_SCALE + tid] * P;
    unsigned short h, l;
    split_bf16(av, h, l);
    ((unsigned short*)(ws + WS_AHT))[(size_t)col * 256 + tid] = h;
    ((unsigned short*)(ws + WS_ALT))[(size_t)col * 256 + tid] = l;
    red[tid] = ws[WS_SHIFT + tid] * P;
    __syncthreads();
    for (int off = 128; off > 0; off >>= 1) {
        if (tid < off) red[tid] += red[tid + off];
        __syncthreads();
    }
    if (tid == 0) ws[WS_C2 + col] = red[0] - cut[col];
}

// ---------------------------------------------------------------------------
// k_gemm1: 128x128 tile, 512 thr = 8 waves (4m x 2n), wave tile 32x64.
// acc[2][4] f32x4 = 32 regs; b-frags loaded per-ni (8 regs live, not 32).
// Epilogue: sigmoid -> fp16 -> LDS [4][128][40] -> coalesced 64B/row stores.
// ---------------------------------------------------------------------------
template <int PRESPLIT>
__global__ __launch_bounds__(512, 1) void k_gemm1(
        const float* __restrict__ x, float* __restrict__ ws) {
    __shared__ __align__(16) char smem_raw[40960];
    short* sb = (short*)smem_raw;

    const int tid  = threadIdx.x;
    const int lane = tid & 63;
    const int wid  = tid >> 6;
    const int lrow = lane & 15;
    const int kgrp = (lane >> 4) * 8;
    const int m0   = (wid >> 1) * 32;
    const int n0   = (wid & 1) * 64;
    const int r0   = blockIdx.x * 128;
    const int c0   = blockIdx.y * 128;

    const unsigned short* AhT = (const unsigned short*)(ws + WS_AHT);
    const unsigned short* AlT = (const unsigned short*)(ws + WS_ALT);
    const unsigned short* XHg = (const unsigned short*)(ws + WS_XH2);
    const unsigned short* XLg = (const unsigned short*)(ws + WS_XL2);
    const float* c2 = ws + WS_C2;

    const int XH = 0, XL = 5120, BHo = 10240, BLo = 15360;   // short offsets

    f32x4 acc[2][4];
#pragma unroll
    for (int mi = 0; mi < 2; ++mi)
#pragma unroll
        for (int ni = 0; ni < 4; ++ni)
#pragma unroll
            for (int rr = 0; rr < 4; ++rr) acc[mi][ni][rr] = 0.f;

    const int r_s = tid >> 2;
    const int kq  = (tid & 3) * 8;
    const size_t xoff = (size_t)(r0 + r_s) * F_DIM + kq;
    const size_t aoff = (size_t)(c0 + r_s) * F_DIM + kq;
    short* xh_dst = sb + XH  + r_s * 40 + kq;
    short* xl_dst = sb + XL  + r_s * 40 + kq;
    short* bh_dst = sb + BHo + r_s * 40 + kq;
    short* bl_dst = sb + BLo + r_s * 40 + kq;

    for (int kc = 0; kc < 256; kc += 32) {
        if (PRESPLIT) {
            *(bf16x8*)xh_dst = *(const bf16x8*)(XHg + xoff + kc);
            *(bf16x8*)xl_dst = *(const bf16x8*)(XLg + xoff + kc);
        } else {
            const float4 a = *(const float4*)(x + xoff + kc);
            const float4 b = *(const float4*)(x + xoff + kc + 4);
            bf16x8 hv, lv;
            unsigned short h, l;
            split_bf16(a.x, h, l); hv[0] = (short)h; lv[0] = (short)l;
            split_bf16(a.y, h, l); hv[1] = (short)h; lv[1] = (short)l;
            split_bf16(a.z, h, l); hv[2] = (short)h; lv[2] = (short)l;
            split_bf16(a.w, h, l); hv[3] = (short)h; lv[3] = (short)l;
            split_bf16(b.x, h, l); hv[4] = (short)h; lv[4] = (short)l;
            split_bf16(b.y, h, l); hv[5] = (short)h; lv[5] = (short)l;
            split_bf16(b.z, h, l); hv[6] = (short)h; lv[6] = (short)l;
            split_bf16(b.w, h, l); hv[7] = (short)h; lv[7] = (short)l;
            *(bf16x8*)xh_dst = hv;
            *(bf16x8*)xl_dst = lv;
        }
        *(bf16x8*)bh_dst = *(const bf16x8*)(AhT + aoff + kc);
        *(bf16x8*)bl_dst = *(const bf16x8*)(AlT + aoff + kc);
        __syncthreads();
#pragma unroll
        for (int ni = 0; ni < 4; ++ni) {
            const int cb = (n0 + ni * 16 + lrow) * 40 + kgrp;
            const bf16x8 bh = *(const bf16x8*)(sb + BHo + cb);
            const bf16x8 bl = *(const bf16x8*)(sb + BLo + cb);
#pragma unroll
            for (int mi = 0; mi < 2; ++mi) {
                const int rb = (m0 + mi * 16 + lrow) * 40 + kgrp;
                const bf16x8 ah = *(const bf16x8*)(sb + XH + rb);
                const bf16x8 al = *(const bf16x8*)(sb + XL + rb);
                acc[mi][ni] = __builtin_amdgcn_mfma_f32_16x16x32_bf16(ah, bh, acc[mi][ni], 0, 0, 0);
                acc[mi][ni] = __builtin_amdgcn_mfma_f32_16x16x32_bf16(al, bh, acc[mi][ni], 0, 0, 0);
                acc[mi][ni] = __builtin_amdgcn_mfma_f32_16x16x32_bf16(ah, bl, acc[mi][ni], 0, 0, 0);
            }
        }
        __syncthreads();
    }

    // epilogue: sigmoid -> fp16 -> LDS [t][row][40] -> coalesced global store
    float c2v[4];
#pragma unroll
    for (int ni = 0; ni < 4; ++ni) c2v[ni] = c2[c0 + n0 + ni * 16 + lrow];

    _Float16* sl = (_Float16*)smem_raw;
#pragma unroll
    for (int mi = 0; mi < 2; ++mi)
#pragma unroll
        for (int ni = 0; ni < 4; ++ni) {
            const int col  = n0 + ni * 16 + lrow;
            const int tl   = col >> 5, s = col & 31;
            const int rbase = m0 + mi * 16 + (lane >> 4) * 4;
#pragma unroll
            for (int rr = 0; rr < 4; ++rr) {
                const float z = acc[mi][ni][rr] + c2v[ni];
                sl[(tl * 128 + rbase + rr) * 40 + s] = (_Float16)(1.0f / (1.0f + expf(-z)));
            }
        }
    __syncthreads();
    {
        const int tl = tid >> 7, rowL = tid & 127;
        const _Float16* srcp = sl + (tl * 128 + rowL) * 40;
        _Float16* dst = (_Float16*)(ws + WS_SCORE) +
                        ((size_t)(blockIdx.y * 4 + tl) * B_ROWS + r0 + rowL) * 32;
        *(uint4*)(dst)      = *(const uint4*)(srcp);
        *(uint4*)(dst + 8)  = *(const uint4*)(srcp + 8);
        *(uint4*)(dst + 16) = *(const uint4*)(srcp + 16);
        *(uint4*)(dst + 24) = *(const uint4*)(srcp + 24);
    }
}

// ---------------------------------------------------------------------------
// k_mlp: 256 thr = 128 rows x 2 tree-halves. Per thread: 1 row, 16 trees.
// Weights broadcast from LDS (staged per tree-pair); h/sc/o in registers.
// Pair-combine via LDS, direct out write (no k_reduce).
// ---------------------------------------------------------------------------
__global__ __launch_bounds__(256) void k_mlp(
        const float* __restrict__ W1g, const float* __restrict__ b1g,
        const float* __restrict__ W2g, const float* __restrict__ twg,
        const float* __restrict__ ws, float* __restrict__ out) {
    __shared__ float w1l[2][1024];
    __shared__ float w2l[2][512];
    __shared__ float b1l[2][32];
    __shared__ float comb[128][17];
    const int tid = threadIdx.x;
    const int rloc = tid & 127;
    const int hf = tid >> 7;
    const int row = blockIdx.x * 128 + rloc;
    const _Float16* score = (const _Float16*)(ws + WS_SCORE);

    float o[16];
#pragma unroll
    for (int j = 0; j < 16; ++j) o[j] = 0.f;

    for (int tt = 0; tt < 16; ++tt) {
        __syncthreads();
        {   // stage weights for trees (tt) and (16+tt)
            const int g = tid >> 7;
            const int gt = g * 16 + tt;
            const int i = tid & 127;
            const float4 a = *(const float4*)&W1g[(size_t)gt * 1024 + i * 8];
            const float4 b = *(const float4*)&W1g[(size_t)gt * 1024 + i * 8 + 4];
            *(float4*)&w1l[g][i * 8]     = a;
            *(float4*)&w1l[g][i * 8 + 4] = b;
            const float4 c = *(const float4*)&W2g[(size_t)gt * 512 + i * 4];
            const int o0 = (i & 3) * 4;
            const float sc = 1.0f / (float)T_TREES;
            w2l[g][i * 4 + 0] = c.x * twg[gt * 16 + o0 + 0] * sc;
            w2l[g][i * 4 + 1] = c.y * twg[gt * 16 + o0 + 1] * sc;
            w2l[g][i * 4 + 2] = c.z * twg[gt * 16 + o0 + 2] * sc;
            w2l[g][i * 4 + 3] = c.w * twg[gt * 16 + o0 + 3] * sc;
            if (i < 32) b1l[g][i] = b1g[gt * 32 + i];
        }
        __syncthreads();
        const int gt = hf * 16 + tt;
        const _Float16* sp = score + ((size_t)gt * B_ROWS + row) * 32;
        const half8 s0 = *(const half8*)(sp);
        const half8 s1 = *(const half8*)(sp + 8);
        const half8 s2 = *(const half8*)(sp + 16);
        const half8 s3 = *(const half8*)(sp + 24);
        float sc[32];
#pragma unroll
        for (int e = 0; e < 8; ++e) {
            sc[e]      = (float)s0[e];
            sc[8 + e]  = (float)s1[e];
            sc[16 + e] = (float)s2[e];
            sc[24 + e] = (float)s3[e];
        }
        float h[32];
#pragma unroll
        for (int j = 0; j < 32; ++j) h[j] = 0.f;
#pragma unroll
        for (int s = 0; s < 32; ++s) {
            const float sv = sc[s];
#pragma unroll
            for (int j4 = 0; j4 < 8; ++j4) {
                const float4 w = *(const float4*)&w1l[hf][s * 32 + j4 * 4];
                h[j4 * 4 + 0] = fmaf(sv, w.x, h[j4 * 4 + 0]);
                h[j4 * 4 + 1] = fmaf(sv, w.y, h[j4 * 4 + 1]);
                h[j4 * 4 + 2] = fmaf(sv, w.z, h[j4 * 4 + 2]);
                h[j4 * 4 + 3] = fmaf(sv, w.w, h[j4 * 4 + 3]);
            }
        }
#pragma unroll
        for (int j = 0; j < 32; ++j) h[j] = fmaxf(h[j] + b1l[hf][j], 0.f);
#pragma unroll
        for (int j = 0; j < 32; ++j) {
            const float hv = h[j];
#pragma unroll
            for (int o4 = 0; o4 < 4; ++o4) {
                const float4 w = *(const float4*)&w2l[hf][j * 16 + o4 * 4];
                o[o4 * 4 + 0] = fmaf(hv, w.x, o[o4 * 4 + 0]);
                o[o4 * 4 + 1] = fmaf(hv, w.y, o[o4 * 4 + 1]);
                o[o4 * 4 + 2] = fmaf(hv, w.z, o[o4 * 4 + 2]);
                o[o4 * 4 + 3] = fmaf(hv, w.w, o[o4 * 4 + 3]);
            }
        }
    }
    __syncthreads();
    if (hf == 1) {
#pragma unroll
        for (int j = 0; j < 16; ++j) comb[rloc][j] = o[j];
    }
    __syncthreads();
    if (hf == 0) {
#pragma unroll
        for (int j = 0; j < 16; ++j)
            out[(size_t)row * 16 + j] = ws[WS_BIAS + j] + o[j] + comb[rloc][j];
    }
}

// ---------------------------------------------------------------------------
// Fused fallback (r9 kernel) for small ws_size.
// ---------------------------------------------------------------------------
template <int ATOMIC>
__global__ __launch_bounds__(512, 1) void k_fused(
        const float* __restrict__ x, const float* __restrict__ W1g,
        const float* __restrict__ b1g, const float* __restrict__ W2g,
        const float* __restrict__ twg, float* __restrict__ ws,
        float* __restrict__ out) {
    __shared__ __align__(16) char smem_raw[40960];
    short* sb = (short*)smem_raw;
    float* sf = (float*)smem_raw;
    const int tid  = threadIdx.x;
    const int lane = tid & 63;
    const int wid  = tid >> 6;
    const int lrow = lane & 15;
    const int kgrp = (lane >> 4) * 8;
    const int m0   = (wid >> 1) * 32;
    const int n0   = (wid & 1) * 64;
    const int r0   = blockIdx.x * 128;
    const int c0   = blockIdx.y * 128;
    const unsigned short* AhT = (const unsigned short*)(ws + WS_AHT);
    const unsigned short* AlT = (const unsigned short*)(ws + WS_ALT);
    const float* c2 = ws + WS_C2;
    const int XH = 0, XL = 5120, BHo = 10240, BLo = 15360;
    const int SCT = 0, HT = 4224, W1T = 8448, W2T = 9600, B1O = 10176;
    f32x4 acc[2][4];
#pragma unroll
    for (int mi = 0; mi < 2; ++mi)
#pragma unroll
        for (int ni = 0; ni < 4; ++ni)
#pragma unroll
            for (int rr = 0; rr < 4; ++rr) acc[mi][ni][rr] = 0.f;
    const int r_s = tid >> 2;
    const int kq  = (tid & 3) * 8;
    const size_t xoff = (size_t)(r0 + r_s) * F_DIM + kq;
    const size_t aoff = (size_t)(c0 + r_s) * F_DIM + kq;
    short* xh_dst = sb + XH  + r_s * 40 + kq;
    short* xl_dst = sb + XL  + r_s * 40 + kq;
    short* bh_dst = sb + BHo + r_s * 40 + kq;
    short* bl_dst = sb + BLo + r_s * 40 + kq;
    for (int kc = 0; kc < 256; kc += 32) {
        const float4 a = *(const float4*)(x + xoff + kc);
        const float4 b = *(const float4*)(x + xoff + kc + 4);
        bf16x8 hv, lv;
        unsigned short h, l;
        split_bf16(a.x, h, l); hv[0] = (short)h; lv[0] = (short)l;
        split_bf16(a.y, h, l); hv[1] = (short)h; lv[1] = (short)l;
        split_bf16(a.z, h, l); hv[2] = (short)h; lv[2] = (short)l;
        split_bf16(a.w, h, l); hv[3] = (short)h; lv[3] = (short)l;
        split_bf16(b.x, h, l); hv[4] = (short)h; lv[4] = (short)l;
        split_bf16(b.y, h, l); hv[5] = (short)h; lv[5] = (short)l;
        split_bf16(b.z, h, l); hv[6] = (short)h; lv[6] = (short)l;
        split_bf16(b.w, h, l); hv[7] = (short)h; lv[7] = (short)l;
        *(bf16x8*)xh_dst = hv;
        *(bf16x8*)xl_dst = lv;
        *(bf16x8*)bh_dst = *(const bf16x8*)(AhT + aoff + kc);
        *(bf16x8*)bl_dst = *(const bf16x8*)(AlT + aoff + kc);
        __syncthreads();
#pragma unroll
        for (int ni = 0; ni < 4; ++ni) {
            const int cb = (n0 + ni * 16 + lrow) * 40 + kgrp;
            const bf16x8 bh = *(const bf16x8*)(sb + BHo + cb);
            const bf16x8 bl = *(const bf16x8*)(sb + BLo + cb);
#pragma unroll
            for (int mi = 0; mi < 2; ++mi) {
                const int rb = (m0 + mi * 16 + lrow) * 40 + kgrp;
                const bf16x8 ah = *(const bf16x8*)(sb + XH + rb);
                const bf16x8 al = *(const bf16x8*)(sb + XL + rb);
                acc[mi][ni] = __builtin_amdgcn_mfma_f32_16x16x32_bf16(ah, bh, acc[mi][ni], 0, 0, 0);
                acc[mi][ni] = __builtin_amdgcn_mfma_f32_16x16x32_bf16(al, bh, acc[mi][ni], 0, 0, 0);
                acc[mi][ni] = __builtin_amdgcn_mfma_f32_16x16x32_bf16(ah, bl, acc[mi][ni], 0, 0, 0);
            }
        }
        __syncthreads();
    }
    float c2v[4];
#pragma unroll
    for (int ni = 0; ni < 4; ++ni) c2v[ni] = c2[c0 + n0 + ni * 16 + lrow];
    const int tx = tid & 15, ty = tid >> 4;
    float acc3[4];
#pragma unroll
    for (int j = 0; j < 4; ++j) acc3[j] = 0.f;
#pragma unroll
    for (int tt = 0; tt < 4; ++tt) {
        const int gt = blockIdx.y * 4 + tt;
        __syncthreads();
        if ((wid & 1) == (tt >> 1)) {
#pragma unroll
            for (int q = 0; q < 2; ++q) {
                const int ni = (tt & 1) * 2 + q;
                const int sl = q * 16 + lrow;
#pragma unroll
                for (int mi = 0; mi < 2; ++mi)
#pragma unroll
                    for (int rr = 0; rr < 4; ++rr) {
                        const float z = acc[mi][ni][rr] + c2v[ni];
                        sf[SCT + sl * 132 + m0 + mi * 16 + (lane >> 4) * 4 + rr] =
                            1.0f / (1.0f + expf(-z));
                    }
            }
        }
        if (tid < 256) {
            const float4 v = *(const float4*)&W1g[(size_t)gt * 1024 + tid * 4];
            const int s = tid >> 3, j0 = (tid & 7) * 4;
            sf[W1T + (j0 + 0) * 36 + s] = v.x;
            sf[W1T + (j0 + 1) * 36 + s] = v.y;
            sf[W1T + (j0 + 2) * 36 + s] = v.z;
            sf[W1T + (j0 + 3) * 36 + s] = v.w;
        }
        if (tid < 128) {
            const float4 v = *(const float4*)&W2g[(size_t)gt * 512 + tid * 4];
            const int j = tid >> 2, o0 = (tid & 3) * 4;
            const float sc = 1.0f / (float)T_TREES;
            sf[W2T + (o0 + 0) * 36 + j] = v.x * twg[gt * 16 + o0 + 0] * sc;
            sf[W2T + (o0 + 1) * 36 + j] = v.y * twg[gt * 16 + o0 + 1] * sc;
            sf[W2T + (o0 + 2) * 36 + j] = v.z * twg[gt * 16 + o0 + 2] * sc;
            sf[W2T + (o0 + 3) * 36 + j] = v.w * twg[gt * 16 + o0 + 3] * sc;
        }
        if (tid < 32) sf[B1O + tid] = b1g[gt * 32 + tid];
        __syncthreads();
        float a20[4], a21[4];
#pragma unroll
        for (int j = 0; j < 4; ++j) { a20[j] = 0.f; a21[j] = 0.f; }
#pragma unroll
        for (int s4 = 0; s4 < 8; ++s4) {
            const float4 wq0 = *(const float4*)&sf[W1T + (2 * tx) * 36 + s4 * 4];
            const float4 wq1 = *(const float4*)&sf[W1T + (2 * tx + 1) * 36 + s4 * 4];
            const float wa0[4] = {wq0.x, wq0.y, wq0.z, wq0.w};
            const float wa1[4] = {wq1.x, wq1.y, wq1.z, wq1.w};
#pragma unroll
            for (int ss = 0; ss < 4; ++ss) {
                const int s = s4 * 4 + ss;
                const float4 sa = *(const float4*)&sf[SCT + s * 132 + ty * 4];
                const float sr[4] = {sa.x, sa.y, sa.z, sa.w};
#pragma unroll
                for (int j = 0; j < 4; ++j) {
                    a20[j] = fmaf(sr[j], wa0[ss], a20[j]);
                    a21[j] = fmaf(sr[j], wa1[ss], a21[j]);
                }
            }
        }
        const float b1a = sf[B1O + 2 * tx];
        const float b1b = sf[B1O + 2 * tx + 1];
#pragma unroll
        for (int j = 0; j < 4; ++j)
            sf[HT + (2 * tx) * 132 + ty * 4 + j] = fmaxf(a20[j] + b1a, 0.f);
#pragma unroll
        for (int j = 0; j < 4; ++j)
            sf[HT + (2 * tx + 1) * 132 + ty * 4 + j] = fmaxf(a21[j] + b1b, 0.f);
        __syncthreads();
#pragma unroll
        for (int j4 = 0; j4 < 8; ++j4) {
            const float4 wq = *(const float4*)&sf[W2T + tx * 36 + j4 * 4];
            const float wa[4] = {wq.x, wq.y, wq.z, wq.w};
#pragma unroll
            for (int u = 0; u < 4; ++u) {
                const int jj = j4 * 4 + u;
                const float4 h0 = *(const float4*)&sf[HT + jj * 132 + ty * 4];
                const float hr[4] = {h0.x, h0.y, h0.z, h0.w};
#pragma unroll
                for (int j = 0; j < 4; ++j) acc3[j] = fmaf(hr[j], wa[u], acc3[j]);
            }
        }
    }
    if (ATOMIC) {
#pragma unroll
        for (int j = 0; j < 4; ++j)
            atomicAdd(&out[(size_t)(r0 + ty * 4 + j) * 16 + tx], acc3[j]);
    } else {
        float* pp = ws + WS_PART + (size_t)blockIdx.y * (B_ROWS * 16);
#pragma unroll
        for (int j = 0; j < 4; ++j)
            pp[(size_t)(r0 + ty * 4 + j) * 16 + tx] = acc3[j];
    }
}

__global__ void k_reduce(const float* __restrict__ ws, float* __restrict__ out) {
    const int idx = blockIdx.x * 256 + threadIdx.x;
    float s = ws[WS_BIAS + (idx & 15)];
#pragma unroll
    for (int cb = 0; cb < 8; ++cb) s += ws[WS_PART + (size_t)cb * 1048576 + idx];
    out[idx] = s;
}

__global__ void k_init_out(const float* __restrict__ ws, float* __restrict__ out) {
    const int idx = blockIdx.x * 256 + threadIdx.x;
    out[idx] = ws[WS_BIAS + (idx & 15)];
}

extern "C" void kernel_launch(void* const* d_in, const int* in_sizes, int n_in,
                              void* d_out, int out_size, void* d_ws, size_t ws_size,
                              hipStream_t stream) {
    (void)in_sizes; (void)n_in; (void)out_size;
    const float* x     = (const float*)d_in[0];
    const float* gamma = (const float*)d_in[1];
    const float* beta  = (const float*)d_in[2];
    const float* fsm   = (const float*)d_in[3];
    const float* cut   = (const float*)d_in[4];
    const float* W1    = (const float*)d_in[5];
    const float* b1    = (const float*)d_in[6];
    const float* W2    = (const float*)d_in[7];
    const float* b2    = (const float*)d_in[8];
    const float* tw    = (const float*)d_in[9];
    float* out = (float*)d_out;
    float* ws  = (float*)d_ws;

    if (ws_size < (size_t)WS_BASE_END * sizeof(float)) return;  // clean fail

    k_zero<<<1, 512, 0, stream>>>(ws);
    k_stats<<<512, 256, 0, stream>>>(x, ws);
    k_finalize<<<1, 256, 0, stream>>>(gamma, beta, b2, tw, ws);
    k_sparsemax<<<1024, 256, 0, stream>>>(fsm, cut, ws);

    if (ws_size >= (size_t)WS_FULL_END * sizeof(float)) {
        k_splitx<<<8192, 256, 0, stream>>>(x, ws);
        k_gemm1<1><<<dim3(512, 8), 512, 0, stream>>>(x, ws);
        k_mlp<<<512, 256, 0, stream>>>(W1, b1, W2, tw, ws, out);
    } else if (ws_size >= (size_t)WS_MID_END * sizeof(float)) {
        k_gemm1<0><<<dim3(512, 8), 512, 0, stream>>>(x, ws);
        k_mlp<<<512, 256, 0, stream>>>(W1, b1, W2, tw, ws, out);
    } else if (ws_size >= (size_t)WS_PART_END * sizeof(float)) {
        k_fused<0><<<dim3(512, 8), 512, 0, stream>>>(x, W1, b1, W2, tw, ws, out);
        k_reduce<<<4096, 256, 0, stream>>>(ws, out);
    } else {
        k_init_out<<<4096, 256, 0, stream>>>(ws, out);
        k_fused<1><<<dim3(512, 8), 512, 0, stream>>>(x, W1, b1, W2, tw, ws, out);
    }
}